// Round 2
// baseline (653.759 us; speedup 1.0000x reference)
//
#include <hip/hip_runtime.h>

// ---------------------------------------------------------------------------
// GCN: 4x GCNConv(128->128) + final linear.
// CSR build with zero global atomics (two-level counting sort).
// Layer pipeline is FUSED: one kernel per layer does
//   aggregate(prev t') -> h tile in LDS (bf16, XOR-swizzled) -> MFMA GEMM
//   with next layer's W (hi/lo bf16 split, read from L2) -> t' (bf16) out.
// Aggregate: 16-lane quarter OWNS one node (no cross-quarter shuffles),
// rotating 4-slot pipeline, edges[] carries pre-multiplied byte offsets.
// (Round 1: resubmission — round-0 bench died to container infra, no verdict.)
// ---------------------------------------------------------------------------

#define SCAN_CHUNK 1024
#define NBUCK_MAX  512
#define BCAP       6144

typedef __attribute__((ext_vector_type(8))) short bf16x8;
typedef __attribute__((ext_vector_type(4))) float f32x4;

__device__ inline unsigned bf16pack(float a, float b) {  // RTNE pack, a->low
    unsigned ua = __float_as_uint(a);
    unsigned ub = __float_as_uint(b);
    ua = (ua + 0x7fffu + ((ua >> 16) & 1u)) >> 16;
    ub = (ub + 0x7fffu + ((ub >> 16) & 1u)) & 0xffff0000u;
    return ua | ub;
}

__device__ inline void split2(float x, ushort& hi, ushort& lo) {
    unsigned u = __float_as_uint(x);
    unsigned r = (u + 0x7fffu + ((u >> 16) & 1u)) & 0xffff0000u;
    hi = (ushort)(r >> 16);
    float rem = x - __uint_as_float(r);
    unsigned u2 = __float_as_uint(rem);
    lo = (ushort)((u2 + 0x7fffu + ((u2 >> 16) & 1u)) >> 16);
}

__device__ inline void bf16x8_expand(uint4 w, float4& a, float4& b) {
    a.x = __uint_as_float(w.x << 16);
    a.y = __uint_as_float(w.x & 0xffff0000u);
    a.z = __uint_as_float(w.y << 16);
    a.w = __uint_as_float(w.y & 0xffff0000u);
    b.x = __uint_as_float(w.z << 16);
    b.y = __uint_as_float(w.z & 0xffff0000u);
    b.z = __uint_as_float(w.w << 16);
    b.w = __uint_as_float(w.w & 0xffff0000u);
}

// ---- W prep: transpose + hi/lo bf16 split of 5 weight matrices ----
__global__ __launch_bounds__(256) void k_prepw(const float* W0, const float* W1,
                                               const float* W2, const float* W3,
                                               const float* W4,
                                               ushort* __restrict__ hiO,
                                               ushort* __restrict__ loO) {
    const float* W = (blockIdx.x == 0) ? W0 : (blockIdx.x == 1) ? W1 :
                     (blockIdx.x == 2) ? W2 : (blockIdx.x == 3) ? W3 : W4;
    ushort* h = hiO + (size_t)blockIdx.x * 16384;
    ushort* l = loO + (size_t)blockIdx.x * 16384;
    for (int idx = threadIdx.x; idx < 4096; idx += 256) {
        int n  = idx >> 5;
        int kq = (idx & 31) * 4;
        ushort hs[4], ls[4];
#pragma unroll
        for (int j = 0; j < 4; j++) split2(W[(kq + j) * 128 + n], hs[j], ls[j]);
        *(uint2*)&h[n * 128 + kq] =
            make_uint2(hs[0] | ((unsigned)hs[1] << 16), hs[2] | ((unsigned)hs[3] << 16));
        *(uint2*)&l[n * 128 + kq] =
            make_uint2(ls[0] | ((unsigned)ls[1] << 16), ls[2] | ((unsigned)ls[3] << 16));
    }
}

// ---- Level-1 pass A: per-block bucket histogram. hist laid out [K][B1]. ----
__global__ __launch_bounds__(256) void k_hist(const int* __restrict__ col,
                                              int* __restrict__ hist,
                                              int E, int K, int B1, int chunk) {
    __shared__ int cnt[NBUCK_MAX];
    int b = blockIdx.x, t = threadIdx.x;
    for (int k = t; k < K; k += 256) cnt[k] = 0;
    __syncthreads();
    int e0 = b * chunk, e1 = min(e0 + chunk, E);
    for (int e = e0 + t; e < e1; e += 256) atomicAdd(&cnt[col[e] >> 8], 1);
    __syncthreads();
    for (int k = t; k < K; k += 256) hist[k * B1 + b] = cnt[k];
}

// ---- 3-phase multi-block exclusive scan ----
__global__ __launch_bounds__(256) void k_scan_part(const int* __restrict__ count,
                                                   int* __restrict__ partials, int n) {
    __shared__ int red[256];
    int t = threadIdx.x;
    int base = blockIdx.x * SCAN_CHUNK + t * 4;
    int s = 0;
#pragma unroll
    for (int j = 0; j < 4; j++) {
        int i = base + j;
        if (i < n) s += count[i];
    }
    red[t] = s;
    __syncthreads();
    for (int off = 128; off > 0; off >>= 1) {
        if (t < off) red[t] += red[t + off];
        __syncthreads();
    }
    if (t == 0) partials[blockIdx.x] = red[0];
}

__global__ __launch_bounds__(1024) void k_scan_top(const int* __restrict__ partials,
                                                   int* __restrict__ blockOff,
                                                   int* __restrict__ result,
                                                   int nb, int n) {
    __shared__ int sums[1024];
    int t = threadIdx.x;
    int v = (t < nb) ? partials[t] : 0;
    sums[t] = v;
    __syncthreads();
    for (int off = 1; off < 1024; off <<= 1) {
        int u = (t >= off) ? sums[t - off] : 0;
        __syncthreads();
        sums[t] += u;
        __syncthreads();
    }
    if (t < nb) blockOff[t] = sums[t] - v;
    if (t == nb - 1) result[n] = sums[t];
}

__global__ __launch_bounds__(256) void k_scan_out(const int* __restrict__ count,
                                                  const int* __restrict__ blockOff,
                                                  int* __restrict__ result, int n) {
    __shared__ int sums[256];
    int t = threadIdx.x;
    int base = blockIdx.x * SCAN_CHUNK + t * 4;
    int c[4]; int s = 0;
#pragma unroll
    for (int j = 0; j < 4; j++) {
        int i = base + j;
        c[j] = (i < n) ? count[i] : 0;
        s += c[j];
    }
    sums[t] = s;
    __syncthreads();
    for (int off = 1; off < 256; off <<= 1) {
        int u = (t >= off) ? sums[t - off] : 0;
        __syncthreads();
        sums[t] += u;
        __syncthreads();
    }
    int run = blockOff[blockIdx.x] + sums[t] - s;
#pragma unroll
    for (int j = 0; j < 4; j++) {
        int i = base + j;
        if (i < n) result[i] = run;
        run += c[j];
    }
}

// ---- Level-1 pass B: scatter edges into bucket-grouped order. ----
__global__ __launch_bounds__(256) void k_scatter(const int* __restrict__ row,
                                                 const int* __restrict__ col,
                                                 const float* __restrict__ ew,
                                                 const int* __restrict__ binBase,
                                                 uint2* __restrict__ etmp,
                                                 int E, int K, int B1, int chunk) {
    __shared__ int cur[NBUCK_MAX];
    int b = blockIdx.x, t = threadIdx.x;
    for (int k = t; k < K; k += 256) cur[k] = binBase[k * B1 + b];
    __syncthreads();
    int e0 = b * chunk, e1 = min(e0 + chunk, E);
    for (int e = e0 + t; e < e1; e += 256) {
        int c = col[e];
        int k = c >> 8;
        int pos = atomicAdd(&cur[k], 1);
        etmp[pos] = make_uint2((unsigned)row[e] | ((unsigned)(c & 255) << 24),
                               __float_as_uint(ew[e]));
    }
}

// ---- Level-2: per-bucket in-LDS counting sort; emit edges/offsets/disq. ----
// edges[].x = src * 256 (pre-multiplied byte offset into the bf16 t' matrix).
__global__ __launch_bounds__(256) void k_bucket(const uint2* __restrict__ etmp,
                                                const int* __restrict__ binBase,
                                                uint2* __restrict__ edges,
                                                int* __restrict__ offsets,
                                                float* __restrict__ disq,
                                                int N, int K, int B1) {
    __shared__ unsigned ls[BCAP];
    __shared__ unsigned lw[BCAP];
    __shared__ int   cnt[256];
    __shared__ float sew[256];
    __shared__ int   excl[257];
    int k = blockIdx.x, t = threadIdx.x;
    int bStart = binBase[k * B1];
    int bEnd   = binBase[(k + 1) * B1];
    int size   = bEnd - bStart;
    cnt[t] = 0; sew[t] = 0.f;
    __syncthreads();
    for (int i = t; i < size && i < BCAP; i += 256) {
        uint2 m = etmp[bStart + i];
        ls[i] = m.x; lw[i] = m.y;
        int j = m.x >> 24;
        atomicAdd(&cnt[j], 1);
        atomicAdd(&sew[j], __uint_as_float(m.y));
    }
    __syncthreads();
    excl[t + 1] = cnt[t];
    if (t == 0) excl[0] = 0;
    __syncthreads();
    for (int off = 1; off < 256; off <<= 1) {
        int add = (t + 1 > off) ? excl[t + 1 - off] : 0;
        __syncthreads();
        excl[t + 1] += add;
        __syncthreads();
    }
    int node = (k << 8) + t;
    if (node < N) {
        offsets[node] = bStart + excl[t];
        disq[node]    = rsqrtf(1.0f + sew[t]);
    }
    if (k == K - 1 && t == 0) offsets[N] = bEnd;
    cnt[t] = excl[t];
    __syncthreads();
    for (int i = t; i < size && i < BCAP; i += 256) {
        unsigned s = ls[i];
        int j = s >> 24;
        int pos = atomicAdd(&cnt[j], 1);
        edges[bStart + pos] = make_uint2((s & 0x00FFFFFFu) << 8, lw[i]);
    }
}

// ---- MFMA GEMM, fp32 A (layer 0 only): split A hi/lo, 3 MFMAs/frag. ----
// D = W^T * h^T; C/D col=node, row=feature quad -> packed bf16 stores.
__global__ __launch_bounds__(256) void k_gemm_f32A(const float* __restrict__ A,
                                                   const ushort* __restrict__ WThi,
                                                   const ushort* __restrict__ WTlo,
                                                   const float* __restrict__ disq,
                                                   unsigned* __restrict__ Cout, int N) {
    __shared__ ushort Whi_s[128][136];
    __shared__ ushort Wlo_s[128][136];
    int tid = threadIdx.x;
#pragma unroll
    for (int r = 0; r < 8; r++) {
        int n  = r * 16 + (tid >> 4);
        int kq = (tid & 15) * 8;
        *(uint4*)&Whi_s[n][kq] = *(const uint4*)&WThi[n * 128 + kq];
        *(uint4*)&Wlo_s[n][kq] = *(const uint4*)&WTlo[n * 128 + kq];
    }
    __syncthreads();

    int wv = tid >> 6, ln = tid & 63;
    int quad = ln >> 4, col = ln & 15;
    int nodeBase = blockIdx.x * 128 + wv * 32;
    int node0 = nodeBase + col, node1 = nodeBase + 16 + col;

    f32x4 acc[2][8];
#pragma unroll
    for (int nb = 0; nb < 2; nb++)
#pragma unroll
        for (int f = 0; f < 8; f++) acc[nb][f] = (f32x4)0.f;

    for (int s = 0; s < 4; s++) {
        int k0 = s * 32 + quad * 8;
        float v0[8], v1[8];
#pragma unroll
        for (int j = 0; j < 8; j++) { v0[j] = 0.f; v1[j] = 0.f; }
        if (node0 < N) {
            float4 a = *(const float4*)&A[(size_t)node0 * 128 + k0];
            float4 b = *(const float4*)&A[(size_t)node0 * 128 + k0 + 4];
            v0[0] = a.x; v0[1] = a.y; v0[2] = a.z; v0[3] = a.w;
            v0[4] = b.x; v0[5] = b.y; v0[6] = b.z; v0[7] = b.w;
        }
        if (node1 < N) {
            float4 a = *(const float4*)&A[(size_t)node1 * 128 + k0];
            float4 b = *(const float4*)&A[(size_t)node1 * 128 + k0 + 4];
            v1[0] = a.x; v1[1] = a.y; v1[2] = a.z; v1[3] = a.w;
            v1[4] = b.x; v1[5] = b.y; v1[6] = b.z; v1[7] = b.w;
        }
        bf16x8 bh0, bl0, bh1, bl1;
#pragma unroll
        for (int j = 0; j < 8; j++) {
            ushort h, l;
            split2(v0[j], h, l); bh0[j] = (short)h; bl0[j] = (short)l;
            split2(v1[j], h, l); bh1[j] = (short)h; bl1[j] = (short)l;
        }
#pragma unroll
        for (int f = 0; f < 8; f++) {
            bf16x8 wh = *(const bf16x8*)&Whi_s[f * 16 + col][k0];
            bf16x8 wl = *(const bf16x8*)&Wlo_s[f * 16 + col][k0];
            acc[0][f] = __builtin_amdgcn_mfma_f32_16x16x32_bf16(wh, bh0, acc[0][f], 0, 0, 0);
            acc[1][f] = __builtin_amdgcn_mfma_f32_16x16x32_bf16(wh, bh1, acc[1][f], 0, 0, 0);
            acc[0][f] = __builtin_amdgcn_mfma_f32_16x16x32_bf16(wl, bh0, acc[0][f], 0, 0, 0);
            acc[1][f] = __builtin_amdgcn_mfma_f32_16x16x32_bf16(wl, bh1, acc[1][f], 0, 0, 0);
            acc[0][f] = __builtin_amdgcn_mfma_f32_16x16x32_bf16(wh, bl0, acc[0][f], 0, 0, 0);
            acc[1][f] = __builtin_amdgcn_mfma_f32_16x16x32_bf16(wh, bl1, acc[1][f], 0, 0, 0);
        }
    }
#pragma unroll
    for (int nb = 0; nb < 2; nb++) {
        int node = nodeBase + nb * 16 + col;
        if (node >= N) continue;
        float d = disq[node];
#pragma unroll
        for (int f = 0; f < 8; f++) {
            f32x4 a = acc[nb][f];
            uint2 u;
            u.x = bf16pack(a[0] * d, a[1] * d);
            u.y = bf16pack(a[2] * d, a[3] * d);
            *(uint2*)&Cout[(size_t)node * 64 + f * 8 + quad * 2] = u;
        }
    }
}

// ---- Fused layer kernel: aggregate 64 nodes -> LDS h tile -> MFMA GEMM. ----
// Aggregate: each 16-lane quarter owns one node (4 nodes/wave, 4 rounds),
// rotating 4-slot gather pipeline, no cross-lane reduction.
// h tile stored bf16 in LDS, 16B chunks XOR-swizzled by (node&7)<<3 ushorts
// so the GEMM-phase ds_read_b128 at node-stride 256B is conflict-light.
// GEMM: D[feat][node] = W^T(hi+lo) * h^T, identical layout to k_gemm_f32A.
// FINAL: no relu on aggregate, fp32 output + out bias, no disq on output.
template <bool FINAL>
__global__ __launch_bounds__(256, 4) void k_fused(const unsigned* __restrict__ tbIn,
                                                  const ushort* __restrict__ WThi,
                                                  const ushort* __restrict__ WTlo,
                                                  const float* __restrict__ aggBias,
                                                  const float* __restrict__ outBias,
                                                  const float* __restrict__ disq,
                                                  const int* __restrict__ offsets,
                                                  const uint2* __restrict__ edges,
                                                  void* __restrict__ outp, int N) {
    __shared__ __align__(16) ushort hs[64 * 128];
    const int tid = threadIdx.x;
    const int wv = tid >> 6, lane = tid & 63;
    const int q = lane >> 4, li = lane & 15;
    const int blockBase = blockIdx.x * 64;
    const char* tbc = (const char*)tbIn;

    // ---------------- aggregate phase ----------------
    float4 bs0 = *(const float4*)&aggBias[li * 8];
    float4 bs1 = *(const float4*)&aggBias[li * 8 + 4];
    float cf[4]; uint4 w[4];
#pragma unroll
    for (int s = 0; s < 4; s++) { cf[s] = 0.f; w[s] = make_uint4(0u, 0u, 0u, 0u); }

#define FETCH(S, II) {                                                     \
        int ii = (II);                                                     \
        if (ii < e1) {                                                     \
            uint2 m = edges[ii];                                           \
            cf[S] = __uint_as_float(m.y);                                  \
            w[S]  = *(const uint4*)(tbc + m.x + (li << 4));                \
        } else cf[S] = 0.f;                                                \
    }
#define CONSUME(S) {                                                       \
        float4 a, b; bf16x8_expand(w[S], a, b);                            \
        float c = cf[S];                                                   \
        acc0.x += c * a.x; acc0.y += c * a.y;                              \
        acc0.z += c * a.z; acc0.w += c * a.w;                              \
        acc1.x += c * b.x; acc1.y += c * b.y;                              \
        acc1.z += c * b.z; acc1.w += c * b.w;                              \
    }

    for (int r = 0; r < 4; r++) {
        int nl   = wv * 16 + r * 4 + q;
        int node = blockBase + nl;
        int e0 = 0, e1 = 0;
        if (node < N) { e0 = offsets[node]; e1 = offsets[node + 1]; }
        float4 acc0 = make_float4(0.f, 0.f, 0.f, 0.f);
        float4 acc1 = make_float4(0.f, 0.f, 0.f, 0.f);

        FETCH(0, e0)
        FETCH(1, e0 + 1)
        FETCH(2, e0 + 2)
        FETCH(3, e0 + 3)
        for (int eb = e0 + 4; eb < e1; eb += 4) {
            CONSUME(0) FETCH(0, eb)
            CONSUME(1) FETCH(1, eb + 1)
            CONSUME(2) FETCH(2, eb + 2)
            CONSUME(3) FETCH(3, eb + 3)
        }
        CONSUME(0) CONSUME(1) CONSUME(2) CONSUME(3)

        if (node < N) {
            float d = disq[node];
            uint4 sv = *(const uint4*)(tbc + ((size_t)node << 8) + (li << 4));
            float4 ta, tb2;
            bf16x8_expand(sv, ta, tb2);
            float4 o0, o1;
            o0.x = d * (acc0.x + ta.x) + bs0.x;
            o0.y = d * (acc0.y + ta.y) + bs0.y;
            o0.z = d * (acc0.z + ta.z) + bs0.z;
            o0.w = d * (acc0.w + ta.w) + bs0.w;
            o1.x = d * (acc1.x + tb2.x) + bs1.x;
            o1.y = d * (acc1.y + tb2.y) + bs1.y;
            o1.z = d * (acc1.z + tb2.z) + bs1.z;
            o1.w = d * (acc1.w + tb2.w) + bs1.w;
            if (!FINAL) {
                o0.x = fmaxf(o0.x, 0.f); o0.y = fmaxf(o0.y, 0.f);
                o0.z = fmaxf(o0.z, 0.f); o0.w = fmaxf(o0.w, 0.f);
                o1.x = fmaxf(o1.x, 0.f); o1.y = fmaxf(o1.y, 0.f);
                o1.z = fmaxf(o1.z, 0.f); o1.w = fmaxf(o1.w, 0.f);
            }
            uint4 u;
            u.x = bf16pack(o0.x, o0.y);
            u.y = bf16pack(o0.z, o0.w);
            u.z = bf16pack(o1.x, o1.y);
            u.w = bf16pack(o1.z, o1.w);
            *(uint4*)&hs[nl * 128 + ((li * 8) ^ ((nl & 7) << 3))] = u;
        }
    }
#undef FETCH
#undef CONSUME
    __syncthreads();

    // ---------------- GEMM phase ----------------
    // wave wv computes feature tiles f0=2*wv, f1=2*wv+1 for all 64 nodes.
    f32x4 accg[2][4];
#pragma unroll
    for (int fs = 0; fs < 2; fs++)
#pragma unroll
        for (int ns = 0; ns < 4; ns++) accg[fs][ns] = (f32x4)0.f;

    for (int s = 0; s < 4; s++) {
        int k0  = s * 32 + q * 8;
        int wr0 = (wv * 32 + li) * 128 + k0;          // row f0*16+li
        bf16x8 wh0 = *(const bf16x8*)&WThi[wr0];
        bf16x8 wl0 = *(const bf16x8*)&WTlo[wr0];
        bf16x8 wh1 = *(const bf16x8*)&WThi[wr0 + 2048]; // +16 rows
        bf16x8 wl1 = *(const bf16x8*)&WTlo[wr0 + 2048];
#pragma unroll
        for (int ns = 0; ns < 4; ns++) {
            int nl = ns * 16 + li;
            bf16x8 b = *(const bf16x8*)&hs[nl * 128 + (k0 ^ ((nl & 7) << 3))];
            accg[0][ns] = __builtin_amdgcn_mfma_f32_16x16x32_bf16(wh0, b, accg[0][ns], 0, 0, 0);
            accg[0][ns] = __builtin_amdgcn_mfma_f32_16x16x32_bf16(wl0, b, accg[0][ns], 0, 0, 0);
            accg[1][ns] = __builtin_amdgcn_mfma_f32_16x16x32_bf16(wh1, b, accg[1][ns], 0, 0, 0);
            accg[1][ns] = __builtin_amdgcn_mfma_f32_16x16x32_bf16(wl1, b, accg[1][ns], 0, 0, 0);
        }
    }

#pragma unroll
    for (int fs = 0; fs < 2; fs++) {
        int f = wv * 2 + fs;
#pragma unroll
        for (int ns = 0; ns < 4; ns++) {
            int node = blockBase + ns * 16 + li;
            if (node >= N) continue;
            if (!FINAL) {
                float d = disq[node];
                f32x4 a = accg[fs][ns];
                uint2 u;
                u.x = bf16pack(a[0] * d, a[1] * d);
                u.y = bf16pack(a[2] * d, a[3] * d);
                *(uint2*)&((unsigned*)outp)[(size_t)node * 64 + f * 8 + q * 2] = u;
            } else {
                int fb = f * 16 + q * 4;
                float4 bv = *(const float4*)&outBias[fb];
                f32x4 a = accg[fs][ns];
                float4 o;
                o.x = a[0] + bv.x; o.y = a[1] + bv.y;
                o.z = a[2] + bv.z; o.w = a[3] + bv.w;
                *(float4*)&((float*)outp)[(size_t)node * 128 + fb] = o;
            }
        }
    }
}

extern "C" void kernel_launch(void* const* d_in, const int* in_sizes, int n_in,
                              void* d_out, int out_size, void* d_ws, size_t ws_size,
                              hipStream_t stream) {
    const float* x    = (const float*)d_in[0];
    const int*   ei   = (const int*)d_in[1];
    const float* ew   = (const float*)d_in[2];
    const float* Wc[4] = {(const float*)d_in[3], (const float*)d_in[5],
                          (const float*)d_in[7], (const float*)d_in[9]};
    const float* bc[4] = {(const float*)d_in[4], (const float*)d_in[6],
                          (const float*)d_in[8], (const float*)d_in[10]};
    const float* Wout = (const float*)d_in[11];
    const float* bout = (const float*)d_in[12];

    const int N = in_sizes[0] / 128;
    const int E = in_sizes[2];
    const int* row = ei;
    const int* col = ei + E;

    const int K     = (N + 255) >> 8;
    const int B1    = 256;
    const int chunk = (E + B1 - 1) / B1;
    const int nScan = K * B1;

    size_t off = 0;
    char* base = (char*)d_ws;
    auto alloc = [&](size_t bytes) -> void* {
        void* p = base + off;
        off += (bytes + 255) & ~(size_t)255;
        return p;
    };
    float*    disq     = (float*)alloc((size_t)N * 4);
    int*      offsets  = (int*)alloc((size_t)(N + 1) * 4);
    int*      hist     = (int*)alloc((size_t)nScan * 4);
    int*      binBase  = (int*)alloc((size_t)(nScan + 1) * 4);
    int*      partials = (int*)alloc(1024 * 4);
    int*      blockOff = (int*)alloc(1024 * 4);
    ushort*   WThi     = (ushort*)alloc((size_t)5 * 16384 * 2);
    ushort*   WTlo     = (ushort*)alloc((size_t)5 * 16384 * 2);
    uint2*    etmp     = (uint2*)alloc((size_t)E * 8);
    uint2*    edges    = (uint2*)alloc((size_t)E * 8);
    unsigned* bufA     = (unsigned*)alloc((size_t)N * 64 * 4);   // bf16 t' ping
    unsigned* bufB     = (unsigned*)alloc((size_t)N * 64 * 4);   // bf16 t' pong

    const int BG  = (N + 127) / 128;
    const int BF  = (N + 63) / 64;
    const int NBs = (nScan + SCAN_CHUNK - 1) / SCAN_CHUNK;

    // Weight prep + CSR build (no global atomics)
    k_prepw<<<5, 256, 0, stream>>>(Wc[0], Wc[1], Wc[2], Wc[3], Wout, WThi, WTlo);
    k_hist<<<B1, 256, 0, stream>>>(col, hist, E, K, B1, chunk);
    k_scan_part<<<NBs, 256, 0, stream>>>(hist, partials, nScan);
    k_scan_top<<<1, 1024, 0, stream>>>(partials, blockOff, binBase, NBs, nScan);
    k_scan_out<<<NBs, 256, 0, stream>>>(hist, blockOff, binBase, nScan);
    k_scatter<<<B1, 256, 0, stream>>>(row, col, ew, binBase, etmp, E, K, B1, chunk);
    k_bucket<<<K, 256, 0, stream>>>(etmp, binBase, edges, offsets, disq, N, K, B1);

    // Layer 0 GEMM: t0 = disq * (x @ W0), bf16 out
    k_gemm_f32A<<<BG, 256, 0, stream>>>(x, WThi, WTlo, disq, bufA, N);
    // Fused layers: aggregate(t_i) -> h -> GEMM W_{i+1} -> t_{i+1}
    k_fused<false><<<BF, 256, 0, stream>>>(bufA, WThi + 16384, WTlo + 16384,
                                           bc[0], nullptr, disq, offsets, edges, bufB, N);
    k_fused<false><<<BF, 256, 0, stream>>>(bufB, WThi + 32768, WTlo + 32768,
                                           bc[1], nullptr, disq, offsets, edges, bufA, N);
    k_fused<false><<<BF, 256, 0, stream>>>(bufA, WThi + 49152, WTlo + 49152,
                                           bc[2], nullptr, disq, offsets, edges, bufB, N);
    // Final: aggregate(t3, no relu) -> h4 -> Wout + bout, fp32 out
    k_fused<true><<<BF, 256, 0, stream>>>(bufB, WThi + 65536, WTlo + 65536,
                                          bc[3], bout, disq, offsets, edges, d_out, N);
}